// Round 9
// baseline (165.910 us; speedup 1.0000x reference)
//
#include <hip/hip_runtime.h>

// SelfAttentionNarrow: B=4, T=2048, EMB=1024, H=16, S=64.
// r9: (1) flash inner loop restructured for within-wave ILP: QK(sub0) and
// QK(sub1) issued back-to-back (independent MFMA chains), then softmax(0)/
// PV(0) and softmax(1)/PV(1) — softmax VALU of one subtile overlaps PV MFMA
// of the other. (2) Wu f32->f16 conversion folded into oproj staging
// (pkrtz in the staging threads); prep shrinks to w3-only.

typedef float f32x4 __attribute__((ext_vector_type(4)));
typedef float f32x16 __attribute__((ext_vector_type(16)));
typedef _Float16 f16x2 __attribute__((ext_vector_type(2)));
typedef _Float16 f16x8 __attribute__((ext_vector_type(8)));
typedef unsigned u32x4 __attribute__((ext_vector_type(4)));

#define MFMA16(a, b, c) __builtin_amdgcn_mfma_f32_16x16x32_f16((a), (b), (c), 0, 0, 0)
#define MFMA32(a, b, c) __builtin_amdgcn_mfma_f32_32x32x16_f16((a), (b), (c), 0, 0, 0)

constexpr int Tn = 2048;
constexpr int Bn = 4;
constexpr int EMBn = 1024;
constexpr float NEG_INF = -3.0e38f;

__device__ __forceinline__ float exp2_hw(float x) {
  float r; asm("v_exp_f32 %0, %1" : "=v"(r) : "v"(x)); return r;
}
__device__ __forceinline__ unsigned pkrtz(float lo, float hi) {
  unsigned r; asm("v_cvt_pkrtz_f16_f32 %0, %1, %2" : "=v"(r) : "v"(lo), "v"(hi)); return r;
}
__device__ __forceinline__ unsigned pkadd(unsigned a, unsigned b) {
  unsigned r; asm("v_pk_add_f16 %0, %1, %2" : "=v"(r) : "v"(a), "v"(b)); return r;
}
__device__ __forceinline__ void permswap(unsigned& a, unsigned& b) {
  asm("v_permlane32_swap_b32 %0, %1" : "+v"(a), "+v"(b));
}

// ---------------------------------------------------------------- prep ----
// w3 only (12288 elements); Wu conversion folded into oproj.
__global__ __launch_bounds__(256) void sa_prep(
    const float* __restrict__ Wk, const float* __restrict__ Wq,
    const float* __restrict__ Wv, _Float16* __restrict__ w3) {
  int idx = blockIdx.x * 256 + threadIdx.x;
  const float rs = 0.21233046f;  // sqrt(log2(e) / 32): logits in log2 units
  if (idx < 4096) {
    w3[idx]        = (_Float16)(Wk[idx] * rs);
    w3[4096 + idx] = (_Float16)(Wq[idx] * rs);
    w3[8192 + idx] = (_Float16)(Wv[idx]);
  }
}

// ----------------------------------------------------------------- qkv ----
__global__ __launch_bounds__(256) void sa_qkv(
    const float* __restrict__ x, const _Float16* __restrict__ w3,
    _Float16* __restrict__ Qb, _Float16* __restrict__ Kb, _Float16* __restrict__ Vt) {
  const int wave = threadIdx.x >> 6;
  const int lane = threadIdx.x & 63;
  const int g = lane >> 4, c = lane & 15;
  const int n = blockIdx.y, b = n >> 4, h = n & 15;
  const int t0 = blockIdx.x * 64 + wave * 16;

  f16x8 ax[2];
#pragma unroll
  for (int kk = 0; kk < 2; ++kk) {
    const float* xp = x + ((long)((b * Tn + t0 + c) * 16 + h)) * 64 + kk * 32 + g * 8;
    f32x4 u = *(const f32x4*)xp;
    f32x4 v = *(const f32x4*)(xp + 4);
    f16x8 a;
    a[0] = (_Float16)u[0]; a[1] = (_Float16)u[1]; a[2] = (_Float16)u[2]; a[3] = (_Float16)u[3];
    a[4] = (_Float16)v[0]; a[5] = (_Float16)v[1]; a[6] = (_Float16)v[2]; a[7] = (_Float16)v[3];
    ax[kk] = a;
  }

#pragma unroll
  for (int w = 0; w < 2; ++w) {
    _Float16* dst = w ? Qb : Kb;
#pragma unroll
    for (int ot = 0; ot < 4; ++ot) {
      f32x4 a_ = {0.f, 0.f, 0.f, 0.f};
#pragma unroll
      for (int kk = 0; kk < 2; ++kk) {
        f16x8 wf = *(const f16x8*)(w3 + w * 4096 + (ot * 16 + c) * 64 + kk * 32 + g * 8);
        a_ = MFMA16(ax[kk], wf, a_);
      }
#pragma unroll
      for (int r = 0; r < 4; ++r)
        dst[((long)n * Tn + t0 + g * 4 + r) * 64 + ot * 16 + c] = (_Float16)a_[r];
    }
  }

  // V^T: D[o][t] = mfma(A=Wv, B=x); Vt[n][s][t]
#pragma unroll
  for (int ot = 0; ot < 4; ++ot) {
    f32x4 a_ = {0.f, 0.f, 0.f, 0.f};
#pragma unroll
    for (int kk = 0; kk < 2; ++kk) {
      f16x8 wf = *(const f16x8*)(w3 + 8192 + (ot * 16 + c) * 64 + kk * 32 + g * 8);
      a_ = MFMA16(wf, ax[kk], a_);
    }
#pragma unroll
    for (int r = 0; r < 4; ++r)
      Vt[((long)n * 64 + ot * 16 + g * 4 + r) * Tn + t0 + c] = (_Float16)a_[r];
  }
}

// --------------------------------------------------------------- flash ----
// 1024 blocks XCD-remapped. 4 waves x 32 q rows. KV tile = 64 (2 subtiles).
// ILP pipeline: QK(0), QK(1) back-to-back; then SM(0)+PV(0), SM(1)+PV(1).
__global__ __launch_bounds__(256, 4) void sa_flash(
    const _Float16* __restrict__ Qb, const _Float16* __restrict__ Kb,
    const _Float16* __restrict__ Vt, const int* __restrict__ pad32,
    _Float16* __restrict__ AO) {
  const int bid = blockIdx.x;
  const int n = (bid & 7) * 8 + (bid >> 7);      // head
  const int qblk = (bid >> 3) & 15;
  const int tid = threadIdx.x;
  const int wave = tid >> 6;
  const int lane = tid & 63;
  const int ql = lane & 31;
  const int hi = lane >> 5;

  int thresh = Tn;
  if (n < Bn) {
    bool is64 = (pad32[1] == 0 && pad32[3] == 0);
    int pv = is64 ? pad32[2 * n] : pad32[n];
    thresh = Tn - pv;
  }

  const int qbase = qblk * 128 + wave * 32;
  const _Float16* Qh = Qb + (long)n * Tn * 64;
  const _Float16* Kh = Kb + (long)n * Tn * 64;
  const _Float16* Vh = Vt + (long)n * 64 * Tn;

  // Q fragments (B-operand): col=q=ql, k=s
  f16x8 bq[4];
  const _Float16* qp = Qh + (long)(qbase + ql) * 64 + hi * 8;
#pragma unroll
  for (int ks = 0; ks < 4; ++ks) bq[ks] = *(const f16x8*)(qp + ks * 16);

  // LDS: K0 @0, K1 @9216, V0 @18432, V1 @27648 (rows 144B-padded)
  __shared__ __align__(16) char smem[36864];

  const int sr = tid >> 2, sc = tid & 3;
  const _Float16* kgp = Kh + sr * 64 + sc * 8;        // + kb*64
  const _Float16* vgp = Vh + (long)sr * Tn + sc * 8;  // + kb
  char* kw = smem + sr * 144 + sc * 16;
  char* vw = smem + 18432 + sr * 144 + sc * 16;

  f32x16 o[2];
  f32x16 zf;
#pragma unroll
  for (int i = 0; i < 16; ++i) { o[0][i] = 0.f; o[1][i] = 0.f; zf[i] = 0.f; }
  float l = 0.f;

  const bool qge = (qbase + ql) >= thresh;
  const bool qany = (qbase + 32) > thresh;

  // prologue: stage tile 0 into buf 0
  {
    f16x8 k0 = *(const f16x8*)kgp;
    f16x8 k1 = *(const f16x8*)(kgp + 32);
    f16x8 v0 = *(const f16x8*)vgp;
    f16x8 v1 = *(const f16x8*)(vgp + 32);
    *(f16x8*)kw = k0;
    *(f16x8*)(kw + 64) = k1;
    *(f16x8*)vw = v0;
    *(f16x8*)(vw + 64) = v1;
  }
  __syncthreads();

  int cur = 0;
  for (int kb = 0; kb < Tn; kb += 64) {
    // issue next tile's staging loads early (wraps on last iter; harmless)
    const int kbn = (kb + 64) & (Tn - 1);
    f16x8 kst0 = *(const f16x8*)(kgp + kbn * 64);
    f16x8 kst1 = *(const f16x8*)(kgp + kbn * 64 + 32);
    f16x8 vst0 = *(const f16x8*)(vgp + kbn);
    f16x8 vst1 = *(const f16x8*)(vgp + kbn + 32);

    const char* kbb = smem + cur * 9216;
    const char* vbb = smem + 18432 + cur * 9216;

    // ---- QK for BOTH subtiles (independent MFMA chains) ----
    f32x16 st[2];
#pragma unroll
    for (int sub = 0; sub < 2; ++sub) {
      const char* krow = kbb + (sub * 32 + ql) * 144 + hi * 16;
      f16x8 ka0 = *(const f16x8*)(krow);
      f16x8 ka1 = *(const f16x8*)(krow + 32);
      f16x8 ka2 = *(const f16x8*)(krow + 64);
      f16x8 ka3 = *(const f16x8*)(krow + 96);
      __builtin_amdgcn_s_setprio(1);
      f32x16 s_ = MFMA32(ka0, bq[0], zf);
      s_ = MFMA32(ka1, bq[1], s_);
      s_ = MFMA32(ka2, bq[2], s_);
      s_ = MFMA32(ka3, bq[3], s_);
      __builtin_amdgcn_s_setprio(0);

      if (qany && (kb + sub * 32 + 32) > thresh) {
        if (qge) {
#pragma unroll
          for (int r = 0; r < 16; ++r) {
            int kr_ = kb + sub * 32 + (r & 3) + 8 * (r >> 2) + 4 * hi;
            if (kr_ >= thresh) s_[r] = NEG_INF;
          }
        }
      }
      st[sub] = s_;
    }

    // ---- softmax(sub) + PV(sub); SM(1) VALU overlaps PV(0) MFMA ----
#pragma unroll
    for (int sub = 0; sub < 2; ++sub) {
      float p[16];
#pragma unroll
      for (int r = 0; r < 16; ++r) p[r] = exp2_hw(st[sub][r]);

      unsigned pw[8], psum[2];
#pragma unroll
      for (int j = 0; j < 2; ++j) {
        unsigned a0 = pkrtz(p[j * 8 + 0], p[j * 8 + 1]);
        unsigned b0 = pkrtz(p[j * 8 + 4], p[j * 8 + 5]);
        unsigned a1 = pkrtz(p[j * 8 + 2], p[j * 8 + 3]);
        unsigned b1 = pkrtz(p[j * 8 + 6], p[j * 8 + 7]);
        psum[j] = pkadd(pkadd(a0, b0), pkadd(a1, b1));
        permswap(a0, b0);
        permswap(a1, b1);
        pw[j * 4 + 0] = a0; pw[j * 4 + 1] = a1;
        pw[j * 4 + 2] = b0; pw[j * 4 + 3] = b1;
      }
      {
        f16x2 ph = __builtin_bit_cast(f16x2, pkadd(psum[0], psum[1]));
        l += (float)ph[0] + (float)ph[1];
      }
      u32x4 u0 = {pw[0], pw[1], pw[2], pw[3]};
      u32x4 u1 = {pw[4], pw[5], pw[6], pw[7]};
      f16x8 pb0 = __builtin_bit_cast(f16x8, u0);
      f16x8 pb1 = __builtin_bit_cast(f16x8, u1);

      const char* vrow0 = vbb + ql * 144 + sub * 64 + hi * 16;
      const char* vrow1 = vrow0 + 32 * 144;
      f16x8 va0 = *(const f16x8*)(vrow0);
      f16x8 va1 = *(const f16x8*)(vrow0 + 32);
      f16x8 va2 = *(const f16x8*)(vrow1);
      f16x8 va3 = *(const f16x8*)(vrow1 + 32);

      __builtin_amdgcn_s_setprio(1);
      o[0] = MFMA32(va0, pb0, o[0]);
      o[0] = MFMA32(va1, pb1, o[0]);
      o[1] = MFMA32(va2, pb0, o[1]);
      o[1] = MFMA32(va3, pb1, o[1]);
      __builtin_amdgcn_s_setprio(0);
    }

    // write next tile into the other buffer, then sync
    char* kwd = kw + (cur ^ 1) * 9216;
    char* vwd = vw + (cur ^ 1) * 9216;
    *(f16x8*)kwd = kst0;
    *(f16x8*)(kwd + 64) = kst1;
    *(f16x8*)vwd = vst0;
    *(f16x8*)(vwd + 64) = vst1;
    __syncthreads();
    cur ^= 1;
  }

  float lf = l + __shfl_xor(l, 32, 64);  // other hi-half holds the other 16 k's
  float linv = 1.0f / lf;

  // O^T -> per-wave region of (now idle) staging smem -> coalesced AO stores.
  _Float16* my = (_Float16*)(smem + wave * 4096);
#pragma unroll
  for (int stile = 0; stile < 2; ++stile) {
#pragma unroll
    for (int r = 0; r < 16; r += 2) {
      unsigned wv = pkrtz(o[stile][r] * linv, o[stile][r + 1] * linv);
      int s = stile * 32 + (r & 3) + 8 * (r >> 2) + 4 * hi;
      *(unsigned*)(my + ql * 64 + (s ^ ((ql & 7) << 3))) = wv;
    }
  }
  asm volatile("s_waitcnt lgkmcnt(0)" ::: "memory");

  const int bb = n >> 4, hh = n & 15;
  const int qr = lane >> 3, s0 = (lane & 7) * 8;
#pragma unroll
  for (int j = 0; j < 4; ++j) {
    int q = j * 8 + qr;
    f16x8 vv = *(const f16x8*)(my + q * 64 + (s0 ^ ((q & 7) << 3)));
    *(f16x8*)(AO + ((long)(bb * Tn + qbase + q)) * EMBn + hh * 64 + s0) = vv;
  }
}

// --------------------------------------------------------------- oproj ----
// Y(8192x1024) = AO @ Wu^T + bu. Block: 128m x 64n. XCD clustering by mblk.
// Wu staged DIRECTLY FROM F32 (pkrtz in staging) — prep's Wu pass removed.
__global__ __launch_bounds__(256, 4) void sa_oproj(
    const _Float16* __restrict__ A, const float* __restrict__ Wu,
    const float* __restrict__ bu, float* __restrict__ Y) {
  const int bid = blockIdx.x;
  const int xcd = bid & 7;
  const int j = bid >> 3;             // 0..127
  const int nstrip = j & 15;
  const int mblk = xcd * 8 + (j >> 4);
  const int tid = threadIdx.x;
  const int wave = tid >> 6;
  const int lane = tid & 63;
  const int ql = lane & 31;
  const int hi = lane >> 5;
  const int mbase = mblk * 128 + wave * 32;
  const int nbase = nstrip * 64;

  // LDS: 2 x (64 rows x 144B) Wu tile (f16)
  __shared__ __align__(16) char bsm[18432];
  const int sr = tid >> 3, sc = tid & 7;
  const float* wg0 = Wu + (long)(nbase + sr) * 1024 + sc * 8;
  const float* wg1 = Wu + (long)(nbase + sr + 32) * 1024 + sc * 8;
  char* ww0 = bsm + sr * 144 + sc * 16;
  char* ww1 = bsm + (sr + 32) * 144 + sc * 16;

  const _Float16* ap = A + (long)(mbase + ql) * 1024 + hi * 8;

  f32x16 acc[2];
#pragma unroll
  for (int i = 0; i < 16; ++i) { acc[0][i] = 0.f; acc[1][i] = 0.f; }

  // f32x8 -> f16x8 staging converter
  auto cvt8 = [](const float* p) -> f16x8 {
    f32x4 a = *(const f32x4*)p;
    f32x4 b = *(const f32x4*)(p + 4);
    unsigned r0, r1, r2, r3;
    asm("v_cvt_pkrtz_f16_f32 %0, %1, %2" : "=v"(r0) : "v"(a[0]), "v"(a[1]));
    asm("v_cvt_pkrtz_f16_f32 %0, %1, %2" : "=v"(r1) : "v"(a[2]), "v"(a[3]));
    asm("v_cvt_pkrtz_f16_f32 %0, %1, %2" : "=v"(r2) : "v"(b[0]), "v"(b[1]));
    asm("v_cvt_pkrtz_f16_f32 %0, %1, %2" : "=v"(r3) : "v"(b[2]), "v"(b[3]));
    u32x4 u = {r0, r1, r2, r3};
    return __builtin_bit_cast(f16x8, u);
  };

  {
    f16x8 w0 = cvt8(wg0);
    f16x8 w1 = cvt8(wg1);
    *(f16x8*)ww0 = w0;
    *(f16x8*)ww1 = w1;
  }
  __syncthreads();

  int cur = 0;
  for (int kb = 0; kb < 1024; kb += 64) {
    const int kbn = (kb + 64) & 1023;
    f16x8 wn0 = cvt8(wg0 + kbn);
    f16x8 wn1 = cvt8(wg1 + kbn);

    f16x8 af[4];
#pragma unroll
    for (int ks = 0; ks < 4; ++ks) af[ks] = *(const f16x8*)(ap + kb + ks * 16);

    const char* bbase = bsm + cur * 9216;
#pragma unroll
    for (int nt = 0; nt < 2; ++nt) {
      const char* brow = bbase + (nt * 32 + ql) * 144;
#pragma unroll
      for (int ks = 0; ks < 4; ++ks) {
        f16x8 bf = *(const f16x8*)(brow + (ks * 2 + hi) * 16);
        acc[nt] = MFMA32(af[ks], bf, acc[nt]);
      }
    }

    *(f16x8*)(ww0 + (cur ^ 1) * 9216) = wn0;
    *(f16x8*)(ww1 + (cur ^ 1) * 9216) = wn1;
    __syncthreads();
    cur ^= 1;
  }

#pragma unroll
  for (int nt = 0; nt < 2; ++nt) {
    float bias = bu[nbase + nt * 32 + ql];
#pragma unroll
    for (int r = 0; r < 16; ++r) {
      int mrow = mbase + (r & 3) + 8 * (r >> 2) + 4 * hi;
      Y[(long)mrow * 1024 + nbase + nt * 32 + ql] = acc[nt][r] + bias;
    }
  }
}

// -------------------------------------------------------------- launch ----
extern "C" void kernel_launch(void* const* d_in, const int* in_sizes, int n_in,
                              void* d_out, int out_size, void* d_ws, size_t ws_size,
                              hipStream_t stream) {
  const float* x  = (const float*)d_in[0];
  const float* Wk = (const float*)d_in[1];
  const float* Wq = (const float*)d_in[2];
  const float* Wv = (const float*)d_in[3];
  const float* Wu = (const float*)d_in[4];
  const float* bu = (const float*)d_in[5];
  const int* pad  = (const int*)d_in[6];
  float* Y = (float*)d_out;

  _Float16* ws  = (_Float16*)d_ws;
  _Float16* w3  = ws;                        // 12288 (pad to 16384)
  _Float16* Qb  = ws + 16384;                // 8388608 each
  _Float16* Kb  = Qb + 8388608;
  _Float16* Vt  = Kb + 8388608;              // V transposed: [n][s][t]
  _Float16* AO  = Vt + 8388608;

  sa_prep<<<16, 256, 0, stream>>>(Wk, Wq, Wv, w3);
  sa_qkv<<<dim3(32, 64), 256, 0, stream>>>(x, w3, Qb, Kb, Vt);
  sa_flash<<<dim3(1024), 256, 0, stream>>>(Qb, Kb, Vt, pad, AO);
  sa_oproj<<<dim3(1024), 256, 0, stream>>>(AO, Wu, bu, Y);
}

// Round 10
// 147.967 us; speedup vs baseline: 1.1213x; 1.1213x over previous
//
#include <hip/hip_runtime.h>

// SelfAttentionNarrow: B=4, T=2048, EMB=1024, H=16, S=64.
// r10: flash is LDS-bound (model vs counters: MFMA 29us=39% ✓, VALU 35us=44% ✓,
// LDS ~48us — the pole; all 4 waves read IDENTICAL K/V fragments). Fix:
// 64 q rows per wave (2 Q-sets, 4 accs) — same LDS reads serve 2x output,
// per-CU LDS traffic halves. 512 blocks, 8 waves/CU, VGPR~190 (lb 256,2).
// prep/oproj reverted to r8 scheme (r9's Wu-fold regressed +13us).

typedef float f32x4 __attribute__((ext_vector_type(4)));
typedef float f32x16 __attribute__((ext_vector_type(16)));
typedef _Float16 f16x2 __attribute__((ext_vector_type(2)));
typedef _Float16 f16x8 __attribute__((ext_vector_type(8)));
typedef unsigned u32x4 __attribute__((ext_vector_type(4)));

#define MFMA16(a, b, c) __builtin_amdgcn_mfma_f32_16x16x32_f16((a), (b), (c), 0, 0, 0)
#define MFMA32(a, b, c) __builtin_amdgcn_mfma_f32_32x32x16_f16((a), (b), (c), 0, 0, 0)

constexpr int Tn = 2048;
constexpr int Bn = 4;
constexpr int EMBn = 1024;
constexpr float NEG_INF = -3.0e38f;

__device__ __forceinline__ float exp2_hw(float x) {
  float r; asm("v_exp_f32 %0, %1" : "=v"(r) : "v"(x)); return r;
}
__device__ __forceinline__ unsigned pkrtz(float lo, float hi) {
  unsigned r; asm("v_cvt_pkrtz_f16_f32 %0, %1, %2" : "=v"(r) : "v"(lo), "v"(hi)); return r;
}
__device__ __forceinline__ unsigned pkadd(unsigned a, unsigned b) {
  unsigned r; asm("v_pk_add_f16 %0, %1, %2" : "=v"(r) : "v"(a), "v"(b)); return r;
}
__device__ __forceinline__ void permswap(unsigned& a, unsigned& b) {
  asm("v_permlane32_swap_b32 %0, %1" : "+v"(a), "+v"(b));
}

// ---------------------------------------------------------------- prep ----
__global__ __launch_bounds__(256) void sa_prep(
    const float* __restrict__ Wk, const float* __restrict__ Wq,
    const float* __restrict__ Wv, const float* __restrict__ Wu,
    _Float16* __restrict__ w3, _Float16* __restrict__ wub) {
  int idx = blockIdx.x * 256 + threadIdx.x;
  const float rs = 0.21233046f;  // sqrt(log2(e) / 32): logits in log2 units
  if (idx < 1048576) wub[idx] = (_Float16)Wu[idx];
  if (idx < 4096) {
    w3[idx]        = (_Float16)(Wk[idx] * rs);
    w3[4096 + idx] = (_Float16)(Wq[idx] * rs);
    w3[8192 + idx] = (_Float16)(Wv[idx]);
  }
}

// ----------------------------------------------------------------- qkv ----
__global__ __launch_bounds__(256) void sa_qkv(
    const float* __restrict__ x, const _Float16* __restrict__ w3,
    _Float16* __restrict__ Qb, _Float16* __restrict__ Kb, _Float16* __restrict__ Vt) {
  const int wave = threadIdx.x >> 6;
  const int lane = threadIdx.x & 63;
  const int g = lane >> 4, c = lane & 15;
  const int n = blockIdx.y, b = n >> 4, h = n & 15;
  const int t0 = blockIdx.x * 64 + wave * 16;

  f16x8 ax[2];
#pragma unroll
  for (int kk = 0; kk < 2; ++kk) {
    const float* xp = x + ((long)((b * Tn + t0 + c) * 16 + h)) * 64 + kk * 32 + g * 8;
    f32x4 u = *(const f32x4*)xp;
    f32x4 v = *(const f32x4*)(xp + 4);
    f16x8 a;
    a[0] = (_Float16)u[0]; a[1] = (_Float16)u[1]; a[2] = (_Float16)u[2]; a[3] = (_Float16)u[3];
    a[4] = (_Float16)v[0]; a[5] = (_Float16)v[1]; a[6] = (_Float16)v[2]; a[7] = (_Float16)v[3];
    ax[kk] = a;
  }

#pragma unroll
  for (int w = 0; w < 2; ++w) {
    _Float16* dst = w ? Qb : Kb;
#pragma unroll
    for (int ot = 0; ot < 4; ++ot) {
      f32x4 a_ = {0.f, 0.f, 0.f, 0.f};
#pragma unroll
      for (int kk = 0; kk < 2; ++kk) {
        f16x8 wf = *(const f16x8*)(w3 + w * 4096 + (ot * 16 + c) * 64 + kk * 32 + g * 8);
        a_ = MFMA16(ax[kk], wf, a_);
      }
#pragma unroll
      for (int r = 0; r < 4; ++r)
        dst[((long)n * Tn + t0 + g * 4 + r) * 64 + ot * 16 + c] = (_Float16)a_[r];
    }
  }

  // V^T: D[o][t] = mfma(A=Wv, B=x); Vt[n][s][t]
#pragma unroll
  for (int ot = 0; ot < 4; ++ot) {
    f32x4 a_ = {0.f, 0.f, 0.f, 0.f};
#pragma unroll
    for (int kk = 0; kk < 2; ++kk) {
      f16x8 wf = *(const f16x8*)(w3 + 8192 + (ot * 16 + c) * 64 + kk * 32 + g * 8);
      a_ = MFMA16(wf, ax[kk], a_);
    }
#pragma unroll
    for (int r = 0; r < 4; ++r)
      Vt[((long)n * 64 + ot * 16 + g * 4 + r) * Tn + t0 + c] = (_Float16)a_[r];
  }
}

// --------------------------------------------------------------- flash ----
// 512 blocks XCD-remapped (8 heads x 8 qblocks per XCD). 4 waves x 64 q rows
// (2 Q-sets per wave). KV tile 64 (2 subtiles). LDS K [64][144B], V [64][144B]
// double-buffered (36.9KB). Same ka/va LDS reads feed both q-halves.
__global__ __launch_bounds__(256, 2) void sa_flash(
    const _Float16* __restrict__ Qb, const _Float16* __restrict__ Kb,
    const _Float16* __restrict__ Vt, const int* __restrict__ pad32,
    _Float16* __restrict__ AO) {
  const int bid = blockIdx.x;
  const int n = (bid & 7) * 8 + (bid >> 6);      // head
  const int qblk = (bid >> 3) & 7;
  const int tid = threadIdx.x;
  const int wave = tid >> 6;
  const int lane = tid & 63;
  const int ql = lane & 31;
  const int hi = lane >> 5;

  int thresh = Tn;
  if (n < Bn) {
    bool is64 = (pad32[1] == 0 && pad32[3] == 0);
    int pv = is64 ? pad32[2 * n] : pad32[n];
    thresh = Tn - pv;
  }

  const int qbase = qblk * 256 + wave * 64;
  const _Float16* Qh = Qb + (long)n * Tn * 64;
  const _Float16* Kh = Kb + (long)n * Tn * 64;
  const _Float16* Vh = Vt + (long)n * 64 * Tn;

  // Q fragments (B-operand) for both q-halves: col=q, k=s
  f16x8 bq[2][4];
#pragma unroll
  for (int qh = 0; qh < 2; ++qh) {
    const _Float16* qp = Qh + (long)(qbase + qh * 32 + ql) * 64 + hi * 8;
#pragma unroll
    for (int ks = 0; ks < 4; ++ks) bq[qh][ks] = *(const f16x8*)(qp + ks * 16);
  }

  // LDS: K0 @0, K1 @9216, V0 @18432, V1 @27648 (rows 144B-padded)
  __shared__ __align__(16) char smem[36864];

  const int sr = tid >> 2, sc = tid & 3;
  const _Float16* kgp = Kh + sr * 64 + sc * 8;        // + kb*64
  const _Float16* vgp = Vh + (long)sr * Tn + sc * 8;  // + kb
  char* kw = smem + sr * 144 + sc * 16;
  char* vw = smem + 18432 + sr * 144 + sc * 16;

  f32x16 o[2][2];
  f32x16 zf;
#pragma unroll
  for (int i = 0; i < 16; ++i) {
    o[0][0][i] = 0.f; o[0][1][i] = 0.f; o[1][0][i] = 0.f; o[1][1][i] = 0.f;
    zf[i] = 0.f;
  }
  float l0 = 0.f, l1 = 0.f;

  const bool qge0 = (qbase + ql) >= thresh;
  const bool qge1 = (qbase + 32 + ql) >= thresh;
  const bool qany = (qbase + 64) > thresh;

  // prologue: stage tile 0 into buf 0
  {
    f16x8 k0 = *(const f16x8*)kgp;
    f16x8 k1 = *(const f16x8*)(kgp + 32);
    f16x8 v0 = *(const f16x8*)vgp;
    f16x8 v1 = *(const f16x8*)(vgp + 32);
    *(f16x8*)kw = k0;
    *(f16x8*)(kw + 64) = k1;
    *(f16x8*)vw = v0;
    *(f16x8*)(vw + 64) = v1;
  }
  __syncthreads();

  int cur = 0;
  for (int kb = 0; kb < Tn; kb += 64) {
    const int kbn = (kb + 64) & (Tn - 1);
    f16x8 kst0 = *(const f16x8*)(kgp + kbn * 64);
    f16x8 kst1 = *(const f16x8*)(kgp + kbn * 64 + 32);
    f16x8 vst0 = *(const f16x8*)(vgp + kbn);
    f16x8 vst1 = *(const f16x8*)(vgp + kbn + 32);

    const char* kbb = smem + cur * 9216;
    const char* vbb = smem + 18432 + cur * 9216;

#pragma unroll
    for (int sub = 0; sub < 2; ++sub) {
      // shared K fragments (identical for both q-halves)
      const char* krow = kbb + (sub * 32 + ql) * 144 + hi * 16;
      f16x8 ka0 = *(const f16x8*)(krow);
      f16x8 ka1 = *(const f16x8*)(krow + 32);
      f16x8 ka2 = *(const f16x8*)(krow + 64);
      f16x8 ka3 = *(const f16x8*)(krow + 96);

      __builtin_amdgcn_s_setprio(1);
      f32x16 st0 = MFMA32(ka0, bq[0][0], zf);
      f32x16 st1 = MFMA32(ka0, bq[1][0], zf);
      st0 = MFMA32(ka1, bq[0][1], st0);
      st1 = MFMA32(ka1, bq[1][1], st1);
      st0 = MFMA32(ka2, bq[0][2], st0);
      st1 = MFMA32(ka2, bq[1][2], st1);
      st0 = MFMA32(ka3, bq[0][3], st0);
      st1 = MFMA32(ka3, bq[1][3], st1);
      __builtin_amdgcn_s_setprio(0);

      if (qany && (kb + sub * 32 + 32) > thresh) {
#pragma unroll
        for (int r = 0; r < 16; ++r) {
          int kr_ = kb + sub * 32 + (r & 3) + 8 * (r >> 2) + 4 * hi;
          if (kr_ >= thresh) {
            if (qge0) st0[r] = NEG_INF;
            if (qge1) st1[r] = NEG_INF;
          }
        }
      }

      // shared V fragments
      const char* vrow0 = vbb + ql * 144 + sub * 64 + hi * 16;
      const char* vrow1 = vrow0 + 32 * 144;
      f16x8 va0 = *(const f16x8*)(vrow0);
      f16x8 va1 = *(const f16x8*)(vrow0 + 32);
      f16x8 va2 = *(const f16x8*)(vrow1);
      f16x8 va3 = *(const f16x8*)(vrow1 + 32);

      // softmax + pack + PV per q-half (VALU of one overlaps MFMA of other)
#pragma unroll
      for (int qh = 0; qh < 2; ++qh) {
        const f32x16& stq = qh ? st1 : st0;
        float p[16];
#pragma unroll
        for (int r = 0; r < 16; ++r) p[r] = exp2_hw(stq[r]);

        unsigned pw[8], psum[2];
#pragma unroll
        for (int j = 0; j < 2; ++j) {
          unsigned a0 = pkrtz(p[j * 8 + 0], p[j * 8 + 1]);
          unsigned b0 = pkrtz(p[j * 8 + 4], p[j * 8 + 5]);
          unsigned a1 = pkrtz(p[j * 8 + 2], p[j * 8 + 3]);
          unsigned b1 = pkrtz(p[j * 8 + 6], p[j * 8 + 7]);
          psum[j] = pkadd(pkadd(a0, b0), pkadd(a1, b1));
          permswap(a0, b0);
          permswap(a1, b1);
          pw[j * 4 + 0] = a0; pw[j * 4 + 1] = a1;
          pw[j * 4 + 2] = b0; pw[j * 4 + 3] = b1;
        }
        {
          f16x2 ph = __builtin_bit_cast(f16x2, pkadd(psum[0], psum[1]));
          if (qh) l1 += (float)ph[0] + (float)ph[1];
          else    l0 += (float)ph[0] + (float)ph[1];
        }
        u32x4 u0 = {pw[0], pw[1], pw[2], pw[3]};
        u32x4 u1 = {pw[4], pw[5], pw[6], pw[7]};
        f16x8 pb0 = __builtin_bit_cast(f16x8, u0);
        f16x8 pb1 = __builtin_bit_cast(f16x8, u1);

        __builtin_amdgcn_s_setprio(1);
        o[qh][0] = MFMA32(va0, pb0, o[qh][0]);
        o[qh][0] = MFMA32(va1, pb1, o[qh][0]);
        o[qh][1] = MFMA32(va2, pb0, o[qh][1]);
        o[qh][1] = MFMA32(va3, pb1, o[qh][1]);
        __builtin_amdgcn_s_setprio(0);
      }
    }

    char* kwd = kw + (cur ^ 1) * 9216;
    char* vwd = vw + (cur ^ 1) * 9216;
    *(f16x8*)kwd = kst0;
    *(f16x8*)(kwd + 64) = kst1;
    *(f16x8*)vwd = vst0;
    *(f16x8*)(vwd + 64) = vst1;
    __syncthreads();
    cur ^= 1;
  }

  float lf0 = l0 + __shfl_xor(l0, 32, 64);
  float lf1 = l1 + __shfl_xor(l1, 32, 64);
  float linv0 = 1.0f / lf0;
  float linv1 = 1.0f / lf1;

  // O^T -> per-wave 8KB region of idle staging smem -> coalesced AO stores
  const int bb = n >> 4, hh = n & 15;
  const int qr = lane >> 3, s0 = (lane & 7) * 8;
  _Float16* my = (_Float16*)(smem + wave * 8192);
#pragma unroll
  for (int qh = 0; qh < 2; ++qh) {
    float linv = qh ? linv1 : linv0;
    _Float16* myq = my + qh * 2048;
#pragma unroll
    for (int stile = 0; stile < 2; ++stile) {
#pragma unroll
      for (int r = 0; r < 16; r += 2) {
        unsigned wv = pkrtz(o[qh][stile][r] * linv, o[qh][stile][r + 1] * linv);
        int s = stile * 32 + (r & 3) + 8 * (r >> 2) + 4 * hi;
        *(unsigned*)(myq + ql * 64 + (s ^ ((ql & 7) << 3))) = wv;
      }
    }
  }
  asm volatile("s_waitcnt lgkmcnt(0)" ::: "memory");

#pragma unroll
  for (int qh = 0; qh < 2; ++qh) {
    _Float16* myq = my + qh * 2048;
#pragma unroll
    for (int j = 0; j < 4; ++j) {
      int q = j * 8 + qr;
      f16x8 vv = *(const f16x8*)(myq + q * 64 + (s0 ^ ((q & 7) << 3)));
      *(f16x8*)(AO + ((long)(bb * Tn + qbase + qh * 32 + q)) * EMBn + hh * 64 + s0) = vv;
    }
  }
}

// --------------------------------------------------------------- oproj ----
// Y(8192x1024) = AO @ Wu^T + bu. Block: 128m x 64n. XCD clustering by mblk.
// Wu (f16, from prep) staged in double-buffered padded LDS (144B rows).
__global__ __launch_bounds__(256, 4) void sa_oproj(
    const _Float16* __restrict__ A, const _Float16* __restrict__ WuB,
    const float* __restrict__ bu, float* __restrict__ Y) {
  const int bid = blockIdx.x;
  const int xcd = bid & 7;
  const int j = bid >> 3;             // 0..127
  const int nstrip = j & 15;
  const int mblk = xcd * 8 + (j >> 4);
  const int tid = threadIdx.x;
  const int wave = tid >> 6;
  const int lane = tid & 63;
  const int ql = lane & 31;
  const int hi = lane >> 5;
  const int mbase = mblk * 128 + wave * 32;
  const int nbase = nstrip * 64;

  __shared__ __align__(16) char bsm[18432];
  const int sr = tid >> 3, sc = tid & 7;
  const _Float16* wg0 = WuB + (long)(nbase + sr) * 1024 + sc * 8;
  const _Float16* wg1 = WuB + (long)(nbase + sr + 32) * 1024 + sc * 8;
  char* ww0 = bsm + sr * 144 + sc * 16;
  char* ww1 = bsm + (sr + 32) * 144 + sc * 16;

  const _Float16* ap = A + (long)(mbase + ql) * 1024 + hi * 8;

  f32x16 acc[2];
#pragma unroll
  for (int i = 0; i < 16; ++i) { acc[0][i] = 0.f; acc[1][i] = 0.f; }

  {
    f16x8 w0 = *(const f16x8*)wg0;
    f16x8 w1 = *(const f16x8*)wg1;
    *(f16x8*)ww0 = w0;
    *(f16x8*)ww1 = w1;
  }
  __syncthreads();

  int cur = 0;
  for (int kb = 0; kb < 1024; kb += 64) {
    const int kbn = (kb + 64) & 1023;
    f16x8 wn0 = *(const f16x8*)(wg0 + kbn);
    f16x8 wn1 = *(const f16x8*)(wg1 + kbn);

    f16x8 af[4];
#pragma unroll
    for (int ks = 0; ks < 4; ++ks) af[ks] = *(const f16x8*)(ap + kb + ks * 16);

    const char* bbase = bsm + cur * 9216;
#pragma unroll
    for (int nt = 0; nt < 2; ++nt) {
      const char* brow = bbase + (nt * 32 + ql) * 144;
#pragma unroll
      for (int ks = 0; ks < 4; ++ks) {
        f16x8 bf = *(const f16x8*)(brow + (ks * 2 + hi) * 16);
        acc[nt] = MFMA32(af[ks], bf, acc[nt]);
      }
    }

    *(f16x8*)(ww0 + (cur ^ 1) * 9216) = wn0;
    *(f16x8*)(ww1 + (cur ^ 1) * 9216) = wn1;
    __syncthreads();
    cur ^= 1;
  }

#pragma unroll
  for (int nt = 0; nt < 2; ++nt) {
    float bias = bu[nbase + nt * 32 + ql];
#pragma unroll
    for (int r = 0; r < 16; ++r) {
      int mrow = mbase + (r & 3) + 8 * (r >> 2) + 4 * hi;
      Y[(long)mrow * 1024 + nbase + nt * 32 + ql] = acc[nt][r] + bias;
    }
  }
}

// -------------------------------------------------------------- launch ----
extern "C" void kernel_launch(void* const* d_in, const int* in_sizes, int n_in,
                              void* d_out, int out_size, void* d_ws, size_t ws_size,
                              hipStream_t stream) {
  const float* x  = (const float*)d_in[0];
  const float* Wk = (const float*)d_in[1];
  const float* Wq = (const float*)d_in[2];
  const float* Wv = (const float*)d_in[3];
  const float* Wu = (const float*)d_in[4];
  const float* bu = (const float*)d_in[5];
  const int* pad  = (const int*)d_in[6];
  float* Y = (float*)d_out;

  _Float16* ws  = (_Float16*)d_ws;
  _Float16* w3  = ws;                        // 12288 (pad to 16384)
  _Float16* wub = ws + 16384;                // 1048576
  _Float16* Qb  = ws + 16384 + 1048576;      // 8388608 each
  _Float16* Kb  = Qb + 8388608;
  _Float16* Vt  = Kb + 8388608;              // V transposed: [n][s][t]
  _Float16* AO  = Vt + 8388608;

  sa_prep<<<4096, 256, 0, stream>>>(Wk, Wq, Wv, Wu, w3, wub);
  sa_qkv<<<dim3(32, 64), 256, 0, stream>>>(x, w3, Qb, Kb, Vt);
  sa_flash<<<dim3(512), 256, 0, stream>>>(Qb, Kb, Vt, pad, AO);
  sa_oproj<<<dim3(1024), 256, 0, stream>>>(AO, wub, bu, Y);
}